// Round 1
// baseline (70.578 us; speedup 1.0000x reference)
//
#include <hip/hip_runtime.h>

#define IGNORE_LABEL 255

constexpr int B      = 8;
constexpr int BANDS  = 31;
constexpr int H      = 512;
constexpr int W      = 512;
constexpr int NMAT   = 16;
constexpr int HW     = H * W;                 // 262144 (2^18)
constexpr long TOTAL_PIX = (long)B * HW;      // 2,097,152
constexpr long TOTAL_Q   = TOTAL_PIX / 4;     // 524,288 quads

__global__ __launch_bounds__(256) void sad_pixelwise_kernel(
    const float* __restrict__ input,      // [B][BANDS][H][W]
    const int*   __restrict__ target,     // [B][1][H][W]
    const float* __restrict__ materials,  // [NMAT][BANDS]
    float*       __restrict__ out)        // [1]
{
    __shared__ float s_mat[NMAT][BANDS];
    __shared__ float s_tn2[NMAT];         // per-material sum of squares
    __shared__ float s_part[4];           // per-wave partials (256 thr = 4 waves)

    const int tid = threadIdx.x;

    // Stage materials into LDS (496 floats).
    for (int i = tid; i < NMAT * BANDS; i += blockDim.x)
        s_mat[i / BANDS][i % BANDS] = materials[i];
    __syncthreads();

    if (tid < NMAT) {
        float s = 0.f;
        #pragma unroll
        for (int c = 0; c < BANDS; ++c) {
            float m = s_mat[tid][c];
            s = fmaf(m, m, s);
        }
        s_tn2[tid] = s;
    }
    __syncthreads();

    float acc = 0.f;

    long q = (long)blockIdx.x * blockDim.x + tid;  // one quad per thread (grid sized exactly)
    if (q < TOTAL_Q) {
        const long pix = q * 4;
        const int  b   = (int)(pix >> 18);         // pix / HW (HW = 2^18)
        const int  off = (int)(pix & (HW - 1));

        const int4 code4 = *(const int4*)&target[(long)b * HW + off];
        const float* ip  = input + (long)b * BANDS * HW + off;

        int codes[4] = { code4.x, code4.y, code4.z, code4.w };
        int safec[4];
        #pragma unroll
        for (int j = 0; j < 4; ++j) {
            int c = (codes[j] == IGNORE_LABEL) ? 0 : codes[j];
            // clamp for memory safety (reference guarantees 0..15 or 255)
            safec[j] = (c < 0) ? 0 : ((c >= NMAT) ? 0 : c);
        }

        float dot[4] = {0.f, 0.f, 0.f, 0.f};
        float xn [4] = {0.f, 0.f, 0.f, 0.f};

        #pragma unroll
        for (int c = 0; c < BANDS; ++c) {
            const float4 v = *(const float4*)&ip[(long)c * HW];
            const float vv[4] = { v.x, v.y, v.z, v.w };
            #pragma unroll
            for (int j = 0; j < 4; ++j) {
                const float m = s_mat[safec[j]][c];
                dot[j] = fmaf(vv[j], m, dot[j]);
                xn [j] = fmaf(vv[j], vv[j], xn[j]);
            }
        }

        #pragma unroll
        for (int j = 0; j < 4; ++j) {
            if (codes[j] != IGNORE_LABEL) {
                const float denom = sqrtf(xn[j] * s_tn2[safec[j]]);
                float cosv = dot[j] / denom;
                cosv = fminf(fmaxf(cosv, -1.f + 1e-7f), 1.f - 1e-7f);
                acc += acosf(cosv);
            }
        }
    }

    // Wave-64 reduction.
    #pragma unroll
    for (int o = 32; o > 0; o >>= 1)
        acc += __shfl_down(acc, o, 64);

    const int wid = tid >> 6;
    if ((tid & 63) == 0) s_part[wid] = acc;
    __syncthreads();

    if (tid == 0) {
        const float s = s_part[0] + s_part[1] + s_part[2] + s_part[3];
        atomicAdd(out, s);
    }
}

extern "C" void kernel_launch(void* const* d_in, const int* in_sizes, int n_in,
                              void* d_out, int out_size, void* d_ws, size_t ws_size,
                              hipStream_t stream) {
    const float* input     = (const float*)d_in[0];
    const int*   target    = (const int*)  d_in[1];
    const float* materials = (const float*)d_in[2];
    float*       out       = (float*)d_out;

    // Harness poisons d_out once and never re-poisons between replays:
    // zero the accumulator ourselves every call (memset nodes are capturable).
    hipMemsetAsync(out, 0, sizeof(float), stream);

    const int block = 256;
    const int grid  = (int)((TOTAL_Q + block - 1) / block);  // 2048
    sad_pixelwise_kernel<<<grid, block, 0, stream>>>(input, target, materials, out);
}

// Round 2
// 48.354 us; speedup vs baseline: 1.4596x; 1.4596x over previous
//
#include <hip/hip_runtime.h>

#define IGNORE_LABEL 255

constexpr int B      = 8;
constexpr int BANDS  = 31;
constexpr int H      = 512;
constexpr int W      = 512;
constexpr int NMAT   = 16;
constexpr int HW     = H * W;                 // 262144 (2^18)
constexpr long TOTAL_PIX = (long)B * HW;      // 2,097,152
constexpr long TOTAL_Q   = TOTAL_PIX / 4;     // 524,288 quads
constexpr int  NBLOCKS   = (int)(TOTAL_Q / 256);  // 2048 (exact)

typedef float  f32x4 __attribute__((ext_vector_type(4)));
typedef int    i32x4 __attribute__((ext_vector_type(4)));

__global__ __launch_bounds__(256) void sad_main_kernel(
    const float* __restrict__ input,      // [B][BANDS][H][W]
    const int*   __restrict__ target,     // [B][1][H][W]
    const float* __restrict__ materials,  // [NMAT][BANDS]
    float*       __restrict__ part)       // [NBLOCKS]
{
    __shared__ float s_mat[NMAT][BANDS];
    __shared__ float s_tn2[NMAT];
    __shared__ float s_part[4];

    const int tid = threadIdx.x;

    // Addressing + target load issued BEFORE the staging barrier so the
    // 16B/lane target read overlaps materials staging.
    const long pix = ((long)blockIdx.x * blockDim.x + tid) * 4;
    const int  b   = (int)(pix >> 18);         // pix / HW (HW = 2^18)
    const int  off = (int)(pix & (HW - 1));

    const i32x4 code4 = __builtin_nontemporal_load(
        (const i32x4*)&target[(long)b * HW + off]);
    const float* ip = input + (long)b * BANDS * HW + off;

    // Stage materials into LDS (496 floats) + per-material ||t||^2.
    for (int i = tid; i < NMAT * BANDS; i += blockDim.x)
        s_mat[i / BANDS][i % BANDS] = materials[i];
    __syncthreads();
    if (tid < NMAT) {
        float s = 0.f;
        #pragma unroll
        for (int c = 0; c < BANDS; ++c) {
            float m = s_mat[tid][c];
            s = fmaf(m, m, s);
        }
        s_tn2[tid] = s;
    }
    __syncthreads();

    int codes[4] = { code4.x, code4.y, code4.z, code4.w };
    int safec[4];
    #pragma unroll
    for (int j = 0; j < 4; ++j) {
        int c = (codes[j] == IGNORE_LABEL) ? 0 : codes[j];
        safec[j] = (c < 0) ? 0 : ((c >= NMAT) ? 0 : c);  // memory-safety clamp
    }

    float dot[4] = {0.f, 0.f, 0.f, 0.f};
    float xn [4] = {0.f, 0.f, 0.f, 0.f};

    #pragma unroll
    for (int c = 0; c < BANDS; ++c) {
        const f32x4 v = __builtin_nontemporal_load((const f32x4*)&ip[(long)c * HW]);
        #pragma unroll
        for (int j = 0; j < 4; ++j) {
            const float m = s_mat[safec[j]][c];
            dot[j] = fmaf(v[j], m, dot[j]);
            xn [j] = fmaf(v[j], v[j], xn[j]);
        }
    }

    float acc = 0.f;
    #pragma unroll
    for (int j = 0; j < 4; ++j) {
        if (codes[j] != IGNORE_LABEL) {
            const float denom = sqrtf(xn[j] * s_tn2[safec[j]]);
            float cosv = dot[j] / denom;
            cosv = fminf(fmaxf(cosv, -1.f + 1e-7f), 1.f - 1e-7f);
            acc += acosf(cosv);
        }
    }

    // Wave-64 reduction, then per-block partial to workspace (no atomics).
    #pragma unroll
    for (int o = 32; o > 0; o >>= 1)
        acc += __shfl_down(acc, o, 64);

    const int wid = tid >> 6;
    if ((tid & 63) == 0) s_part[wid] = acc;
    __syncthreads();
    if (tid == 0)
        part[blockIdx.x] = s_part[0] + s_part[1] + s_part[2] + s_part[3];
}

__global__ __launch_bounds__(256) void sad_reduce_kernel(
    const float* __restrict__ part,  // [NBLOCKS]
    float*       __restrict__ out)   // [1]
{
    __shared__ float s_part[4];
    const int tid = threadIdx.x;

    float acc = 0.f;
    #pragma unroll
    for (int i = 0; i < NBLOCKS / 256; ++i)   // 8 each
        acc += part[i * 256 + tid];

    #pragma unroll
    for (int o = 32; o > 0; o >>= 1)
        acc += __shfl_down(acc, o, 64);

    const int wid = tid >> 6;
    if ((tid & 63) == 0) s_part[wid] = acc;
    __syncthreads();
    if (tid == 0)
        out[0] = s_part[0] + s_part[1] + s_part[2] + s_part[3];
}

extern "C" void kernel_launch(void* const* d_in, const int* in_sizes, int n_in,
                              void* d_out, int out_size, void* d_ws, size_t ws_size,
                              hipStream_t stream) {
    const float* input     = (const float*)d_in[0];
    const int*   target    = (const int*)  d_in[1];
    const float* materials = (const float*)d_in[2];
    float*       out       = (float*)d_out;
    float*       part      = (float*)d_ws;   // 2048 floats = 8 KB scratch

    sad_main_kernel<<<NBLOCKS, 256, 0, stream>>>(input, target, materials, part);
    sad_reduce_kernel<<<1, 256, 0, stream>>>(part, out);
}